// Round 1
// baseline (117.950 us; speedup 1.0000x reference)
//
#include <hip/hip_runtime.h>
#include <math.h>

#define INFBITS 0x7F800000u
#define TCHUNK 1024

// ---------- block-wide sum (blockDim.x == 256, 4 waves) ----------
__device__ __forceinline__ float block_sum256(float v) {
#pragma unroll
    for (int o = 32; o > 0; o >>= 1) v += __shfl_down(v, o, 64);
    __shared__ float sb[4];
    if ((threadIdx.x & 63) == 0) sb[threadIdx.x >> 6] = v;
    __syncthreads();
    float r = sb[0] + sb[1] + sb[2] + sb[3];
    __syncthreads();   // safe for repeated calls
    return r;
}

// ---------- init: set per-point min slots to +inf ----------
__global__ void init_min(unsigned int* __restrict__ minarr, int n) {
    int i = blockIdx.x * blockDim.x + threadIdx.x;
    if (i < n) minarr[i] = INFBITS;
}

// ---------- dice partial sums (float4 vectorized) ----------
__global__ void dice_partial(const float4* __restrict__ p4, const float4* __restrict__ t4,
                             int n4, float* __restrict__ inter_p, float* __restrict__ uni_p) {
    float inter = 0.f, uni = 0.f;
    for (int i = blockIdx.x * blockDim.x + threadIdx.x; i < n4;
         i += gridDim.x * blockDim.x) {
        float4 p = p4[i];
        float4 t = t4[i];
        float s;
        s = 1.f / (1.f + expf(-p.x)); inter += s * t.x; uni += s + t.x;
        s = 1.f / (1.f + expf(-p.y)); inter += s * t.y; uni += s + t.y;
        s = 1.f / (1.f + expf(-p.z)); inter += s * t.z; uni += s + t.z;
        s = 1.f / (1.f + expf(-p.w)); inter += s * t.w; uni += s + t.w;
    }
    float bi = block_sum256(inter);
    float bu = block_sum256(uni);
    if (threadIdx.x == 0) {
        inter_p[blockIdx.x] = bi;
        uni_p[blockIdx.x]   = bu;
    }
}

// ---------- chamfer: per-point min over one target chunk ----------
// grid = (ceil(maxNM/256), ceil(maxNM/TCHUNK), 2); dir 0: pred->target, dir 1: target->pred
__global__ void chamfer_min_kernel(const float2* __restrict__ P, const float2* __restrict__ T,
                                   int N, int M,
                                   unsigned int* __restrict__ m0,
                                   unsigned int* __restrict__ m1) {
    const float2* A; const float2* B; unsigned int* marr; int nA, nB;
    if (blockIdx.z == 0) { A = P; B = T; marr = m0; nA = N; nB = M; }
    else                 { A = T; B = P; marr = m1; nA = M; nB = N; }

    int tbase = blockIdx.y * TCHUNK;
    if (tbase >= nB) return;                      // uniform per block
    int lim = min(TCHUNK, nB - tbase);

    __shared__ float2 bt[TCHUNK];
    for (int j = threadIdx.x; j < lim; j += blockDim.x) bt[j] = B[tbase + j];
    __syncthreads();

    int pi = blockIdx.x * blockDim.x + threadIdx.x;
    if (pi >= nA) return;                         // no syncs after this
    float2 p = A[pi];

    float mn = __uint_as_float(INFBITS);
#pragma unroll 8
    for (int j = 0; j < lim; ++j) {
        float dx = p.x - bt[j].x;
        float dy = p.y - bt[j].y;
        float d2 = fmaf(dy, dy, dx * dx);
        mn = fminf(mn, d2);
    }
    // d2 >= 0 -> float bit pattern is monotone as uint
    atomicMin(&marr[pi], __float_as_uint(mn));
}

// ---------- finalize: reduce partials, combine, write scalar ----------
__global__ void finalize_kernel(const float* __restrict__ inter_p,
                                const float* __restrict__ uni_p, int nblk,
                                const unsigned int* __restrict__ m0,
                                const unsigned int* __restrict__ m1,
                                int N, int M, float* __restrict__ out) {
    float inter = 0.f, uni = 0.f;
    for (int i = threadIdx.x; i < nblk; i += blockDim.x) {
        inter += inter_p[i];
        uni   += uni_p[i];
    }
    float c0 = 0.f, c1 = 0.f;
    for (int i = threadIdx.x; i < N; i += blockDim.x) c0 += __uint_as_float(m0[i]);
    for (int i = threadIdx.x; i < M; i += blockDim.x) c1 += __uint_as_float(m1[i]);

    float bi  = block_sum256(inter);
    float bu  = block_sum256(uni);
    float bc0 = block_sum256(c0);
    float bc1 = block_sum256(c1);

    if (threadIdx.x == 0) {
        const float SMOOTH = 1e-6f;
        float dice    = (2.f * bi + SMOOTH) / (bu + SMOOTH);
        float chamfer = bc0 / (float)N + bc1 / (float)M;
        out[0] = 0.5f * (1.f - dice) + 0.5f * chamfer;
    }
}

extern "C" void kernel_launch(void* const* d_in, const int* in_sizes, int n_in,
                              void* d_out, int out_size, void* d_ws, size_t ws_size,
                              hipStream_t stream) {
    const float*  pred = (const float*)d_in[0];
    const float*  targ = (const float*)d_in[1];
    const float2* pp   = (const float2*)d_in[2];
    const float2* tp   = (const float2*)d_in[3];
    int n = in_sizes[0];            // 4*1*1024*1024, divisible by 4
    int N = in_sizes[2] / 2;        // 8192 pred points
    int M = in_sizes[3] / 2;        // 8192 target points
    float* out = (float*)d_out;

    // workspace layout:
    //   [0, 2048)    : inter partials (512 floats)
    //   [2048, 4096) : union partials (512 floats)
    //   [8192, ...)  : min arrays, N + M uints
    char* ws = (char*)d_ws;
    const int DICE_BLOCKS = 512;
    float*        inter_p = (float*)ws;
    float*        uni_p   = inter_p + DICE_BLOCKS;
    unsigned int* m0      = (unsigned int*)(ws + 8192);
    unsigned int* m1      = m0 + N;

    int nmin = N + M;
    init_min<<<(nmin + 255) / 256, 256, 0, stream>>>(m0, nmin);

    dice_partial<<<DICE_BLOCKS, 256, 0, stream>>>((const float4*)pred,
                                                  (const float4*)targ,
                                                  n / 4, inter_p, uni_p);

    int maxNM = N > M ? N : M;
    dim3 cgrid((unsigned)((maxNM + 255) / 256),
               (unsigned)((maxNM + TCHUNK - 1) / TCHUNK), 2);
    chamfer_min_kernel<<<cgrid, 256, 0, stream>>>(pp, tp, N, M, m0, m1);

    finalize_kernel<<<1, 256, 0, stream>>>(inter_p, uni_p, DICE_BLOCKS,
                                           m0, m1, N, M, out);
}

// Round 2
// 47.341 us; speedup vs baseline: 2.4915x; 2.4915x over previous
//
#include <hip/hip_runtime.h>
#include <math.h>

#define INFBITS 0x7F800000u
#define TCH 128          // target points staged per block
#define PTS 8            // query points per thread
#define DICE_BLOCKS 512

// ---------- block-wide sum (blockDim.x == 256, 4 waves) ----------
__device__ __forceinline__ float block_sum256(float v) {
#pragma unroll
    for (int o = 32; o > 0; o >>= 1) v += __shfl_down(v, o, 64);
    __shared__ float sb[4];
    if ((threadIdx.x & 63) == 0) sb[threadIdx.x >> 6] = v;
    __syncthreads();
    float r = sb[0] + sb[1] + sb[2] + sb[3];
    __syncthreads();
    return r;
}

// ---------- init (atomic fallback only) ----------
__global__ void init_min(unsigned int* __restrict__ m, int n) {
    int i = blockIdx.x * blockDim.x + threadIdx.x;
    if (i < n) m[i] = INFBITS;
}

// ---------- dice partial sums (float4 vectorized) ----------
__global__ void dice_partial(const float4* __restrict__ p4, const float4* __restrict__ t4,
                             int n4, float* __restrict__ inter_p, float* __restrict__ uni_p) {
    float inter = 0.f, uni = 0.f;
    for (int i = blockIdx.x * blockDim.x + threadIdx.x; i < n4;
         i += gridDim.x * blockDim.x) {
        float4 p = p4[i];
        float4 t = t4[i];
        float s;
        s = 1.f / (1.f + expf(-p.x)); inter += s * t.x; uni += s + t.x;
        s = 1.f / (1.f + expf(-p.y)); inter += s * t.y; uni += s + t.y;
        s = 1.f / (1.f + expf(-p.z)); inter += s * t.z; uni += s + t.z;
        s = 1.f / (1.f + expf(-p.w)); inter += s * t.w; uni += s + t.w;
    }
    float bi = block_sum256(inter);
    float bu = block_sum256(uni);
    if (threadIdx.x == 0) {
        inter_p[blockIdx.x] = bi;
        uni_p[blockIdx.x]   = bu;
    }
}

// ---------- chamfer partial mins ----------
// grid = (ceil(npm/(PTS*256)), chm, 2). dir 0: pred->target, dir 1: target->pred
// Expanded form: d2 = sa + (sb - 2*dot); min over (sb - 2*dot), add sa once.
__global__ void chamfer_partial(const float2* __restrict__ P, const float2* __restrict__ T,
                                int N, int M,
                                float* __restrict__ pm, int npm, int dstride,
                                int use_atomic) {
    int dir = blockIdx.z;
    const float2* A = dir ? T : P;
    const float2* B = dir ? P : T;
    int nA = dir ? M : N;
    int nB = dir ? N : M;

    int tb = blockIdx.y * TCH;
    if (tb >= nB) return;                      // uniform per block

    __shared__ float4 bs[TCH];
    int t = threadIdx.x;
    if (t < TCH) {
        float bx = 0.f, by = 0.f, sb2 = __uint_as_float(INFBITS);
        if (tb + t < nB) {
            float2 b = B[tb + t];
            bx = b.x; by = b.y;
            sb2 = fmaf(bx, bx, by * by);
        }
        bs[t] = make_float4(bx, by, sb2, 0.f);
    }
    __syncthreads();

    int abase = blockIdx.x * (PTS * 256);
    float nx[PTS], ny[PTS], sa[PTS], mn[PTS];
#pragma unroll
    for (int i = 0; i < PTS; ++i) {
        int p = abase + i * 256 + t;
        nx[i] = 0.f; ny[i] = 0.f; sa[i] = 0.f;
        mn[i] = __uint_as_float(INFBITS);
        if (p < nA) {
            float2 a = A[p];
            nx[i] = -2.f * a.x;
            ny[i] = -2.f * a.y;
            sa[i] = fmaf(a.x, a.x, a.y * a.y);
        }
    }

#pragma unroll 4
    for (int j = 0; j < TCH; ++j) {
        float4 b = bs[j];
#pragma unroll
        for (int i = 0; i < PTS; ++i) {
            float v = fmaf(nx[i], b.x, fmaf(ny[i], b.y, b.z));
            mn[i] = fminf(mn[i], v);
        }
    }

    float* dst = pm + (size_t)dir * dstride;
    if (use_atomic) {
#pragma unroll
        for (int i = 0; i < PTS; ++i) {
            int p = abase + i * 256 + t;
            if (p < nA)
                atomicMin((unsigned int*)dst + p, __float_as_uint(mn[i] + sa[i]));
        }
    } else {
        float* dstc = dst + (size_t)blockIdx.y * npm;
#pragma unroll
        for (int i = 0; i < PTS; ++i) {
            int p = abase + i * 256 + t;
            if (p < nA) dstc[p] = mn[i] + sa[i];
        }
    }
}

// ---------- fin1: min across chunks, per-point; block-sum ----------
__global__ void chamfer_fin1(const float* __restrict__ pm, int npm, int dstride,
                             int N, int M, int nch0, int nch1,
                             float* __restrict__ bsum, int gx) {
    int dir = blockIdx.y;
    int nA  = dir ? M : N;
    int nch = dir ? nch1 : nch0;
    int p = blockIdx.x * 256 + threadIdx.x;
    float v = 0.f;
    if (p < nA) {
        const float* src = pm + (size_t)dir * dstride + p;
        v = __uint_as_float(INFBITS);
        for (int c = 0; c < nch; ++c) v = fminf(v, src[(size_t)c * npm]);
    }
    float s = block_sum256(v);
    if (threadIdx.x == 0) bsum[dir * gx + blockIdx.x] = s;
}

// ---------- fin2: combine everything ----------
__global__ void fin2(const float* __restrict__ inter_p, const float* __restrict__ uni_p,
                     int nblk, const float* __restrict__ bsum, int gx,
                     int N, int M, float* __restrict__ out) {
    float inter = 0.f, uni = 0.f, c0 = 0.f, c1 = 0.f;
    for (int i = threadIdx.x; i < nblk; i += 256) { inter += inter_p[i]; uni += uni_p[i]; }
    for (int i = threadIdx.x; i < gx;   i += 256) { c0 += bsum[i]; c1 += bsum[gx + i]; }
    float bi  = block_sum256(inter);
    float bu  = block_sum256(uni);
    float bc0 = block_sum256(c0);
    float bc1 = block_sum256(c1);
    if (threadIdx.x == 0) {
        const float SMOOTH = 1e-6f;
        float dice    = (2.f * bi + SMOOTH) / (bu + SMOOTH);
        float chamfer = bc0 / (float)N + bc1 / (float)M;
        out[0] = 0.5f * (1.f - dice) + 0.5f * chamfer;
    }
}

extern "C" void kernel_launch(void* const* d_in, const int* in_sizes, int n_in,
                              void* d_out, int out_size, void* d_ws, size_t ws_size,
                              hipStream_t stream) {
    const float*  pred = (const float*)d_in[0];
    const float*  targ = (const float*)d_in[1];
    const float2* pp   = (const float2*)d_in[2];
    const float2* tp   = (const float2*)d_in[3];
    int n = in_sizes[0];
    int N = in_sizes[2] / 2;
    int M = in_sizes[3] / 2;
    float* out = (float*)d_out;

    int npm  = N > M ? N : M;
    int nch0 = (M + TCH - 1) / TCH;     // chunks for dir 0 (targets)
    int nch1 = (N + TCH - 1) / TCH;     // chunks for dir 1 (preds)
    int chm  = nch0 > nch1 ? nch0 : nch1;
    int gx_pts = (npm + PTS * 256 - 1) / (PTS * 256);
    int gx_fin = (npm + 255) / 256;

    size_t tail_bytes = (size_t)(DICE_BLOCKS * 2 + 2 * gx_fin + 64) * 4;
    size_t pm_full    = (size_t)2 * chm * npm * 4;
    size_t pm_atomic  = (size_t)2 * npm * 4;
    int use_atomic = (ws_size < pm_full + tail_bytes) ? 1 : 0;
    size_t pm_bytes = use_atomic ? pm_atomic : pm_full;
    int dstride = use_atomic ? npm : chm * npm;   // per-direction stride (elements)

    char* ws = (char*)d_ws;
    float* pm = (float*)ws;
    size_t off = (pm_bytes + 255) & ~(size_t)255;
    float* inter_p = (float*)(ws + off);
    float* uni_p   = inter_p + DICE_BLOCKS;
    float* bsum    = uni_p + DICE_BLOCKS;

    if (use_atomic) {
        int nmin = 2 * npm;
        init_min<<<(nmin + 255) / 256, 256, 0, stream>>>((unsigned int*)pm, nmin);
    }

    dice_partial<<<DICE_BLOCKS, 256, 0, stream>>>((const float4*)pred,
                                                  (const float4*)targ,
                                                  n / 4, inter_p, uni_p);

    dim3 cgrid((unsigned)gx_pts, (unsigned)chm, 2);
    chamfer_partial<<<cgrid, 256, 0, stream>>>(pp, tp, N, M, pm, npm, dstride,
                                               use_atomic);

    int nch0_eff = use_atomic ? 1 : nch0;
    int nch1_eff = use_atomic ? 1 : nch1;
    dim3 fgrid((unsigned)gx_fin, 2);
    chamfer_fin1<<<fgrid, 256, 0, stream>>>(pm, npm, dstride, N, M,
                                            nch0_eff, nch1_eff, bsum, gx_fin);

    fin2<<<1, 256, 0, stream>>>(inter_p, uni_p, DICE_BLOCKS, bsum, gx_fin, N, M, out);
}

// Round 3
// 38.464 us; speedup vs baseline: 3.0665x; 1.2308x over previous
//
#include <hip/hip_runtime.h>
#include <math.h>

#define INFBITS 0x7F800000u
#define TCH 256          // target points staged per chamfer block
#define PTS 8            // query points per thread
#define DICE_BLOCKS 512

// ---------- block-wide sum (blockDim.x == 256, 4 waves) ----------
__device__ __forceinline__ float block_sum256(float v) {
#pragma unroll
    for (int o = 32; o > 0; o >>= 1) v += __shfl_down(v, o, 64);
    __shared__ float sb[4];
    if ((threadIdx.x & 63) == 0) sb[threadIdx.x >> 6] = v;
    __syncthreads();
    float r = sb[0] + sb[1] + sb[2] + sb[3];
    __syncthreads();
    return r;
}

// ---------- K1: fused dice partials + chamfer partial mins ----------
// blocks [0, DICE_BLOCKS)            : dice grid-stride partial sums
// blocks [DICE_BLOCKS, +2*gxp*chm)   : chamfer, dir = upper half
__global__ void __launch_bounds__(256) fused_partials(
        const float4* __restrict__ p4, const float4* __restrict__ t4, int n4,
        float* __restrict__ inter_p, float* __restrict__ uni_p,
        const float2* __restrict__ P, const float2* __restrict__ T,
        int N, int M, float* __restrict__ pm, int npm, int chm, int gxp,
        unsigned int* __restrict__ counter) {
    int bid = blockIdx.x;
    if (bid == 0 && threadIdx.x == 0) *counter = 0u;   // reset K2's semaphore

    if (bid < DICE_BLOCKS) {
        float inter = 0.f, uni = 0.f;
        for (int i = bid * 256 + threadIdx.x; i < n4; i += DICE_BLOCKS * 256) {
            float4 p = p4[i];
            float4 t = t4[i];
            float s;
            s = __fdividef(1.f, 1.f + __expf(-p.x)); inter = fmaf(s, t.x, inter); uni += s + t.x;
            s = __fdividef(1.f, 1.f + __expf(-p.y)); inter = fmaf(s, t.y, inter); uni += s + t.y;
            s = __fdividef(1.f, 1.f + __expf(-p.z)); inter = fmaf(s, t.z, inter); uni += s + t.z;
            s = __fdividef(1.f, 1.f + __expf(-p.w)); inter = fmaf(s, t.w, inter); uni += s + t.w;
        }
        float bi = block_sum256(inter);
        float bu = block_sum256(uni);
        if (threadIdx.x == 0) { inter_p[bid] = bi; uni_p[bid] = bu; }
        return;
    }

    // ---- chamfer partials ----
    int cb      = bid - DICE_BLOCKS;
    int per_dir = gxp * chm;
    int dir     = cb / per_dir;
    int rem     = cb - dir * per_dir;
    int cy      = rem / gxp;          // target chunk
    int cx      = rem - cy * gxp;     // query-point group
    const float2* A = dir ? T : P;
    const float2* B = dir ? P : T;
    int nA = dir ? M : N;
    int nB = dir ? N : M;

    int tb = cy * TCH;
    if (tb >= nB) return;             // uniform per block

    __shared__ float4 bs[TCH];
    int t = threadIdx.x;
    for (int j = t; j < TCH; j += 256) {
        float bx = 0.f, by = 0.f, s2 = __uint_as_float(INFBITS);
        if (tb + j < nB) {
            float2 b = B[tb + j];
            bx = b.x; by = b.y;
            s2 = fmaf(bx, bx, by * by);
        }
        bs[j] = make_float4(bx, by, s2, 0.f);   // OOB pads with +inf -> never wins min
    }
    __syncthreads();

    int abase = cx * (PTS * 256);
    float nx[PTS], ny[PTS], sa[PTS], mn[PTS];
#pragma unroll
    for (int i = 0; i < PTS; ++i) {
        int p = abase + i * 256 + t;
        nx[i] = 0.f; ny[i] = 0.f; sa[i] = 0.f;
        mn[i] = __uint_as_float(INFBITS);
        if (p < nA) {
            float2 a = A[p];
            nx[i] = -2.f * a.x;
            ny[i] = -2.f * a.y;
            sa[i] = fmaf(a.x, a.x, a.y * a.y);
        }
    }

#pragma unroll 4
    for (int j = 0; j < TCH; ++j) {
        float4 b = bs[j];
#pragma unroll
        for (int i = 0; i < PTS; ++i) {
            mn[i] = fminf(mn[i], fmaf(nx[i], b.x, fmaf(ny[i], b.y, b.z)));
        }
    }

    float* dstc = pm + ((size_t)dir * chm + cy) * npm;
#pragma unroll
    for (int i = 0; i < PTS; ++i) {
        int p = abase + i * 256 + t;
        if (p < nA) dstc[p] = mn[i] + sa[i];
    }
}

// ---------- K2: fused finalize ----------
// grid = 2*gxf blocks; per-point min across chunks + block sum; last block combines.
__global__ void __launch_bounds__(256) finalize_all(
        const float* __restrict__ pm, int npm, int chm,
        int N, int M, int nch0, int nch1,
        const float* __restrict__ inter_p, const float* __restrict__ uni_p,
        float* __restrict__ bsum, unsigned int* __restrict__ counter,
        int gxf, float* __restrict__ out) {
    int blk = blockIdx.x;
    int dir = blk / gxf;
    int bx  = blk - dir * gxf;
    int nA  = dir ? M : N;
    int nch = dir ? nch1 : nch0;

    int p = bx * 256 + threadIdx.x;
    float v = 0.f;
    if (p < nA) {
        const float* src = pm + (size_t)dir * chm * npm + p;
        v = __uint_as_float(INFBITS);
        for (int c = 0; c < nch; ++c) v = fminf(v, src[(size_t)c * npm]);
    }
    float s = block_sum256(v);

    __shared__ int is_last;
    if (threadIdx.x == 0) {
        bsum[blk] = s;
        __threadfence();
        unsigned int old = atomicAdd(counter, 1u);
        is_last = (old == (unsigned)(2 * gxf - 1));
    }
    __syncthreads();
    if (!is_last) return;
    __threadfence();

    float inter = 0.f, uni = 0.f, c0 = 0.f, c1 = 0.f;
    for (int i = threadIdx.x; i < DICE_BLOCKS; i += 256) {
        inter += inter_p[i];
        uni   += uni_p[i];
    }
    const volatile float* vb = bsum;
    for (int i = threadIdx.x; i < gxf; i += 256) {
        c0 += vb[i];
        c1 += vb[gxf + i];
    }
    float bi  = block_sum256(inter);
    float bu  = block_sum256(uni);
    float bc0 = block_sum256(c0);
    float bc1 = block_sum256(c1);
    if (threadIdx.x == 0) {
        const float SMOOTH = 1e-6f;
        float dice    = (2.f * bi + SMOOTH) / (bu + SMOOTH);
        float chamfer = bc0 / (float)N + bc1 / (float)M;
        out[0] = 0.5f * (1.f - dice) + 0.5f * chamfer;
    }
}

extern "C" void kernel_launch(void* const* d_in, const int* in_sizes, int n_in,
                              void* d_out, int out_size, void* d_ws, size_t ws_size,
                              hipStream_t stream) {
    const float*  pred = (const float*)d_in[0];
    const float*  targ = (const float*)d_in[1];
    const float2* pp   = (const float2*)d_in[2];
    const float2* tp   = (const float2*)d_in[3];
    int n = in_sizes[0];
    int N = in_sizes[2] / 2;
    int M = in_sizes[3] / 2;
    float* out = (float*)d_out;

    int npm  = N > M ? N : M;
    int nch0 = (M + TCH - 1) / TCH;
    int nch1 = (N + TCH - 1) / TCH;
    int chm  = nch0 > nch1 ? nch0 : nch1;
    int gxp  = (npm + PTS * 256 - 1) / (PTS * 256);
    int gxf  = (npm + 255) / 256;

    // ws layout: pm | inter_p | uni_p | bsum | counter
    char*  ws      = (char*)d_ws;
    float* pm      = (float*)ws;
    size_t pm_bytes = (size_t)2 * chm * npm * sizeof(float);
    size_t off     = (pm_bytes + 255) & ~(size_t)255;
    float* inter_p = (float*)(ws + off);
    float* uni_p   = inter_p + DICE_BLOCKS;
    float* bsum    = uni_p + DICE_BLOCKS;
    unsigned int* counter = (unsigned int*)(bsum + 2 * gxf);

    int cham_blocks = 2 * gxp * chm;
    fused_partials<<<DICE_BLOCKS + cham_blocks, 256, 0, stream>>>(
        (const float4*)pred, (const float4*)targ, n / 4,
        inter_p, uni_p, pp, tp, N, M, pm, npm, chm, gxp, counter);

    finalize_all<<<2 * gxf, 256, 0, stream>>>(pm, npm, chm, N, M, nch0, nch1,
                                              inter_p, uni_p, bsum, counter,
                                              gxf, out);
}